// Round 16
// baseline (18.065 us; speedup 1.0000x reference)
//
#include <hip/hip_runtime.h>
#include <math.h>

// JPEG layer: RGB->YCbCr, clip/shift, 2x2 chroma pool (sub-OFF after), 8x8 DCT,
// quantize, round. FINAL = round-9 structure (best measured, 17.97us):
// one 256-thread WG per 32x32 tile; each thread owns a 2x2 pixel quad ->
// pooling in registers; Y and pooled chroma stored TRANSPOSED ([col][row],
// strides 36/20) so DCT stage-1 column reads are 2x ds_read_b128; DCT is
// 8 threads per 8x8 block, one pass (stage-1 column-owner -> wave-private TMP
// -> stage-2 row-owner), no barrier inside (intra-wave LDS RAW is in-order).
// Bit-exact vs np reference: clip/shift chroma sub-OFF AFTER the pool mean;
// reference-order sums; no-FMA denominator; rintf round-half-even.
//
// Ten structural variants (rounds 6-15) all landed at 18 +/- 1 us or worse:
// this formulation is pinned at ~4.2 TB/s effective on a mixed read+write
// stream (67% of the 6.3 TB/s pure-copy ceiling; harness poison-fills evict
// L3 between replays so reads are true HBM reads). Practical roofline.

static __device__ __forceinline__ float clip01(float v) {
    return fminf(fmaxf(v, 0.0f), 1.0f);
}

// DCT-II 8x8 matrix as compile-time f32 constants: f32(0.5*cos(k*pi/16)).
// Row 0 = 1/sqrt(8), which equals M4 bitwise in f32.
#define M1f 0.49039264020161522f
#define M2f 0.46193976625564337f
#define M3f 0.41573480615127262f
#define M4f 0.35355339059327376f
#define M5f 0.27778511650980111f
#define M6f 0.19134171618254489f
#define M7f 0.097545161008064134f

static constexpr float Dm[8][8] = {
    { M4f,  M4f,  M4f,  M4f,  M4f,  M4f,  M4f,  M4f},
    { M1f,  M3f,  M5f,  M7f, -M7f, -M5f, -M3f, -M1f},
    { M2f,  M6f, -M6f, -M2f, -M2f, -M6f,  M6f,  M2f},
    { M3f, -M7f, -M1f, -M5f,  M5f,  M1f,  M7f, -M3f},
    { M4f, -M4f, -M4f,  M4f,  M4f, -M4f, -M4f,  M4f},
    { M5f, -M1f,  M7f,  M3f, -M3f, -M7f,  M1f, -M5f},
    { M6f, -M2f,  M2f, -M6f, -M6f,  M2f, -M2f,  M6f},
    { M7f, -M5f,  M3f, -M1f,  M1f, -M3f,  M5f, -M7f},
};

__global__ __launch_bounds__(256)
void jpeg_kernel(const float* __restrict__ rgb, const float* __restrict__ quant,
                 float* __restrict__ out)
{
    // single shared block with integer offsets -> guaranteed ds addressing
    __shared__ __align__(16) float smem[3616];
    constexpr int YTT = 0;     // transposed Y [32 cols][36]
    constexpr int CBT = 1152;  // transposed pooled cb [16 cols][20]
    constexpr int CRT = 1472;  // transposed pooled cr [16 cols][20]
    constexpr int QNT = 1792;  // quant [3][64]
    constexpr int TMP = 1984;  // DCT temp: 4 waves * 6 blocks * 68

    const int t = threadIdx.x;

    // stage quant into LDS (covered by the barrier)
    if (t < 192) smem[QNT + t] = quant[t];

    const int wg   = blockIdx.x;
    const int b    = wg >> 8;         // image index (256 tiles per image)
    const int tile = wg & 255;
    const int th   = tile >> 4;       // tile row 0..15
    const int tw   = tile & 15;       // tile col 0..15

    // ---- color transform + in-register 2x2 pooling: one quad per thread ----
    {
        const int qr = t >> 4;             // quad row 0..15
        const int qc = t & 15;             // quad col 0..15
        const int r0 = 2 * qr, c0 = 2 * qc;
        const float* p = rgb + ((size_t)b * 3) * 262144 + (size_t)(th * 32 + r0) * 512 + (tw * 32 + c0);
        const float2 R0 = *(const float2*)p;
        const float2 R1 = *(const float2*)(p + 512);
        const float2 G0 = *(const float2*)(p + 262144);
        const float2 G1 = *(const float2*)(p + 262656);
        const float2 B0 = *(const float2*)(p + 524288);
        const float2 B1 = *(const float2*)(p + 524800);
        const float OFF = (float)(128.0 / 255.0);
        // order: 0=w00, 1=w01, 2=w10, 3=w11
        const float rr[4] = {R0.x, R0.y, R1.x, R1.y};
        const float gg[4] = {G0.x, G0.y, G1.x, G1.y};
        const float bb[4] = {B0.x, B0.y, B1.x, B1.y};
        float yv[4], cbv[4], crv[4];
        #pragma unroll
        for (int k = 0; k < 4; ++k) {
            const float r_ = rr[k], g_ = gg[k], b_ = bb[k];
            const float y  = (float)(0.299) * r_ + (float)(0.587) * g_ + (float)(0.114) * b_;
            const float cb = (float)(-0.168735892) * r_ + (float)(-0.331264108) * g_ + 0.5f * b_;
            const float cr = 0.5f * r_ + (float)(-0.418687589) * g_ + (float)(-0.081312411) * b_;
            yv[k]  = clip01(y) - OFF;
            cbv[k] = clip01(cb + OFF);     // clipped, pre-subtract (subtract after pool)
            crv[k] = clip01(cr + OFF);
        }
        // transposed Y writes: column c holds Y[r][c] at YTT + c*36 + r
        *(float2*)&smem[YTT + c0 * 36 + r0]       = make_float2(yv[0], yv[2]);
        *(float2*)&smem[YTT + (c0 + 1) * 36 + r0] = make_float2(yv[1], yv[3]);
        // in-register pool, exact reference order ((w00+w01)+w10)+w11, then -OFF
        float sb = cbv[0];
        sb = sb + cbv[1];
        sb = sb + cbv[2];
        sb = sb + cbv[3];
        smem[CBT + qc * 20 + qr] = sb * 0.25f - OFF;
        float sr = crv[0];
        sr = sr + crv[1];
        sr = sr + crv[2];
        sr = sr + crv[3];
        smem[CRT + qc * 20 + qr] = sr * 0.25f - OFF;
    }
    __syncthreads();

    // ---- DCT + quantize: 8 threads per 8x8 block, one pass ----
    const int w  = t >> 6;           // wave 0..3
    const int l  = t & 63;
    const int bi = l >> 3;           // block-in-wave 0..5 (6,7 idle)
    const int lc = l & 7;            // stage-1 column / stage-2 row

    if (bi < 6) {
        const int sb = w * 6 + bi;   // block 0..23
        int xaddr, ch; size_t obase;
        if (sb < 16) {               // Y: 4x4 grid of 8x8 in the 32x32 tile
            const int sr = sb >> 2, sc = sb & 3;
            xaddr = YTT + (sc * 8 + lc) * 36 + sr * 8; ch = 0;
            obase = (((size_t)(b * 64 + th * 4 + sr)) * 64 + (tw * 4 + sc)) * 64;
        } else if (sb < 20) {        // Cb: 2x2 grid in pooled 16x16
            const int s = sb - 16, sr = s >> 1, sc = s & 1;
            xaddr = CBT + (sc * 8 + lc) * 20 + sr * 8; ch = 1;
            obase = (size_t)4194304 + (((size_t)(b * 32 + th * 2 + sr)) * 32 + (tw * 2 + sc)) * 64;
        } else {                     // Cr
            const int s = sb - 20, sr = s >> 1, sc = s & 1;
            xaddr = CRT + (sc * 8 + lc) * 20 + sr * 8; ch = 2;
            obase = (size_t)5242880 + (((size_t)(b * 32 + th * 2 + sr)) * 32 + (tw * 2 + sc)) * 64;
        }

        // stage 1: thread owns column lc; X column is contiguous (transposed
        // layout) -> 2x ds_read_b128. T[i] = sum_j D[i][j] * X[j][lc],
        // j-ascending fmac chain (bit-exact).
        float x[8];
        *(float4*)&x[0] = *(const float4*)&smem[xaddr];
        *(float4*)&x[4] = *(const float4*)&smem[xaddr + 4];
        const int tbase = TMP + w * 408 + bi * 68;   // 68-dword pad, 16B-aligned
        #pragma unroll
        for (int i = 0; i < 8; ++i) {
            float s = 0.0f;
            #pragma unroll
            for (int j = 0; j < 8; ++j) s += Dm[i][j] * x[j];
            smem[tbase + i * 8 + lc] = s;
        }

        // stage 2: thread owns row lc of T (intra-wave RAW, no barrier —
        // bit-validated rounds 7-15)
        float tr[8], q[8];
        *(float4*)&tr[0] = *(const float4*)&smem[tbase + lc * 8];
        *(float4*)&tr[4] = *(const float4*)&smem[tbase + lc * 8 + 4];
        *(float4*)&q[0]  = *(const float4*)&smem[QNT + ch * 64 + lc * 8];
        *(float4*)&q[4]  = *(const float4*)&smem[QNT + ch * 64 + lc * 8 + 4];

        const float qadd = (float)(0.5 / 255.0);
        float o[8];
        #pragma unroll
        for (int cc = 0; cc < 8; ++cc) {
            float s = 0.0f;
            #pragma unroll
            for (int k = 0; k < 8; ++k) s += tr[k] * Dm[cc][k];   // k-ascending
            // denominator: mul/add separately rounded (no FMA), matches numpy
            const float den = __fadd_rn(__fmul_rn(q[cc], 2.5f), qadd);
            o[cc] = rintf(s / den);      // IEEE div + round-half-even, matches np
        }
        float* op = out + obase + lc * 8;
        *(float4*)&op[0] = make_float4(o[0], o[1], o[2], o[3]);
        *(float4*)&op[4] = make_float4(o[4], o[5], o[6], o[7]);
    }
}

extern "C" void kernel_launch(void* const* d_in, const int* in_sizes, int n_in,
                              void* d_out, int out_size, void* d_ws, size_t ws_size,
                              hipStream_t stream) {
    const float* rgb   = (const float*)d_in[0];
    const float* quant = (const float*)d_in[1];
    float* out = (float*)d_out;
    dim3 grid(4096), block(256);
    hipLaunchKernelGGL(jpeg_kernel, grid, block, 0, stream, rgb, quant, out);
}